// Round 2
// 99.889 us; speedup vs baseline: 1.0430x; 1.0430x over previous
//
#include <hip/hip_runtime.h>

// (B,C,H,W) = (4,64,64,64) -> N=4096, Cr=8. Single-head attn, d_k=8, d_v=64.
#define BB 4
#define CC 64
#define NN 4096

typedef __attribute__((ext_vector_type(8)))  short short8;
typedef __attribute__((ext_vector_type(4)))  short short4v;
typedef __attribute__((ext_vector_type(4)))  float f32x4;
typedef __attribute__((ext_vector_type(16))) float f32x16;
typedef unsigned short u16;

// workspace (all bf16): qws [B*N][8], kws [B*N][8], vws [B*64][N] (V transposed)
#define QWS_ELEMS (BB * NN * 8)

__device__ inline u16 f2bf(float x) {
    unsigned u = __float_as_uint(x);
    u = (u + 0x7fffu + ((u >> 16) & 1u)) >> 16;   // RNE
    return (u16)u;
}
__device__ inline unsigned pack2rne(float a, float b) {
    return (unsigned)f2bf(a) | ((unsigned)f2bf(b) << 16);
}
// truncating bf16 pack of two floats in one v_perm_b32 (P only; 6x error headroom)
__device__ inline unsigned permpack(float lo, float hi) {
    return __builtin_amdgcn_perm(__float_as_uint(hi), __float_as_uint(lo), 0x07060302);
}

// Barrier with LDS-only drain: does NOT wait vmcnt, so global prefetches
// stay in flight across the barrier (correctness needs only ds ordering:
// staging ds_writes and fragment ds_reads both retire via lgkmcnt).
__device__ inline void barrier_lgkm() {
    asm volatile("s_waitcnt lgkmcnt(0)\n\ts_barrier" ::: "memory");
}

union SH8 {
    short8 s;
    struct Halves { short4v lo, hi; } h;
    uint4 u;
};

// ---------------------------------------------------------------------------
// Kernel 1: QKV projection. Grid (32, 8) x 512 thr = 256 blocks (1/CU),
// 1 pixel/thread. BALANCED slices: block y computes v[8y..8y+8) plus a
// 2-channel q-pair (y<4: q[2y,2y+1]) or k-pair (y>=4: k[2y-8,2y-7]) ->
// uniform 640 FMA/thread (old: 512/1024 mix + 288-block tail on 256 CUs).
// Streaming form: one coalesced x load per channel feeding 10 FMAs.
// NOTE: softmax exp stays __expf (compiler-known v_mul+v_exp). A raw
// inline-asm v_exp_f32 variant produced NaN: TRANS-op hazard handling is
// keyed on producer opcode, which inline asm hides from the hazard
// recognizer -> consumer read stale regs. Do not hand-write trans ops.
// ---------------------------------------------------------------------------
__global__ __launch_bounds__(512) void proj_kernel(
    const float* __restrict__ x,
    const float* __restrict__ wq, const float* __restrict__ bq,
    const float* __restrict__ wk, const float* __restrict__ bk,
    const float* __restrict__ wv, const float* __restrict__ bv,
    u16* __restrict__ ws_u)
{
    u16* qws = ws_u;
    u16* kws = ws_u + QWS_ELEMS;
    u16* vws = ws_u + 2 * QWS_ELEMS;

    const int y   = blockIdx.y;                    // 0..7, block-uniform
    const int pix = blockIdx.x * 512 + threadIdx.x;
    const int b   = pix >> 12;
    const int n   = pix & (NN - 1);
    const float* xb = x + ((size_t)b << 18) + n;

    const int v0  = y << 3;
    const int isq = (y < 4) ? 1 : 0;
    const int qc0 = (y & 3) << 1;                  // channel pair within q|k
    const float* wj = isq ? wq : wk;               // block-uniform -> SGPR
    const float* bj = isq ? bq : bk;

    float av[8];
    float a0 = bj[qc0], a1 = bj[qc0 + 1];
#pragma unroll
    for (int i = 0; i < 8; ++i) av[i] = bv[v0 + i];
#pragma unroll 8
    for (int c = 0; c < CC; ++c) {
        const float xv = xb[(size_t)c << 12];      // coalesced 256B/wave
#pragma unroll
        for (int i = 0; i < 8; ++i)
            av[i] += wv[(v0 + i) * CC + c] * xv;   // scalar (uniform) loads
        a0 += wj[qc0 * CC + c] * xv;
        a1 += wj[(qc0 + 1) * CC + c] * xv;
    }
#pragma unroll
    for (int i = 0; i < 8; ++i)
        vws[(((size_t)((b << 6) + v0 + i)) << 12) + n] = f2bf(av[i]);

    u16* dst = (isq ? qws : kws) + (size_t)pix * 8 + qc0;
    *(unsigned*)dst = pack2rne(a0, a1);            // 4B store (even u16 offset)
}

// ---------------------------------------------------------------------------
// Kernel 2: fused 32x32x16-MFMA flash attention. Block 512 thr (8 waves =
// 4 m-chunks x 2 q-halves), 64 q/block, 128-key tiles, 32 iters, ONE
// lgkm-only barrier per iter (global prefetches never drained). S^T = K*Q^T
// per wave; exp'd S D-frag repacked IN-REGISTER to the PV A-frag via a
// permuted k-slot order; V B-frags gathered from LDS with the SAME
// permutation (2x ds_read_b64 each). P never touches LDS. V staged
// global->LDS double-buffered (132-u16 padded rows). Prefetches issued at
// top-of-iter for max in-flight span. Per-wave PV partials tree-reduced;
// epilogue stages scaled result to LDS so ALL 512 threads do the residual
// add with coalesced 32B x/out accesses.
// ---------------------------------------------------------------------------
__global__ __launch_bounds__(512) void attn_kernel(
    const float* __restrict__ x, const float* __restrict__ gamma,
    const u16* __restrict__ ws_u, float* __restrict__ out)
{
    const u16* qws = ws_u;
    const u16* kws = ws_u + QWS_ELEMS;
    const u16* vws = ws_u + 2 * QWS_ELEMS;

    // smem: v_t [2][64*132] u16 (33792 B) ALIASED with eb [8][64*17] f32
    // (34816 B, reduce blobs) ALIASED with eb2 [64][69] f32 (17664 B, final
    // staging), then l_part, l_inv.
    __shared__ __align__(16) char smem[34816 + 1024 + 256];
    u16*   v_t    = (u16*)smem;                    // [2][64*132]
    float* eb     = (float*)smem;                  // [8][64*17]
    float* eb2    = (float*)smem;                  // [64][69]
    float* l_part = (float*)(smem + 34816);        // [8][32]
    float* l_inv  = (float*)(smem + 34816 + 1024); // [2][32], holds gamma/l

    const int tid  = threadIdx.x;
    const int w    = tid >> 6;
    const int lane = tid & 63;
    const int l31  = lane & 31;
    const int lh   = lane >> 5;
    const int mh   = w >> 1;       // 0..3 m-chunk
    const int qh   = w & 1;        // 0..1 q-half

    const int b  = blockIdx.y;
    const int qb = blockIdx.x << 6;   // 64 queries/block
    const int bN = b << 12;

    // S fragments (lanes>=32 supply k-slots 8..15 = zero; only 8 real ch)
    short8 qf = {0,0,0,0,0,0,0,0};
    short8 kf = {0,0,0,0,0,0,0,0};
    if (lane < 32) {
        qf = *(const short8*)(qws + (size_t)(bN + qb + (qh << 5) + l31) * 8);
        kf = *(const short8*)(kws + (size_t)(bN + (mh << 5) + l31) * 8);
    }
    short8 kn = kf;

    // V staging: thread -> (row c_st, octets o_st, o_st+64) of the 128-m tile
    const int c_st = tid >> 3;
    const int o_st = (tid & 7) << 3;                 // u16 offset of octet
    const u16* vgr = vws + (((size_t)((b << 6) + c_st)) << 12) + o_st;
    const int st0  = c_st * 132 + o_st;              // 132-u16 padded rows

    SH8 va0, va1, vb0, vb1;
    va0.s = *(const short8*)(vgr);                   // tile 0
    va1.s = *(const short8*)(vgr + 64);
    *(short4v*)&v_t[st0]      = va0.h.lo;            // b64 writes (8B-aligned)
    *(short4v*)&v_t[st0 + 4]  = va0.h.hi;
    *(short4v*)&v_t[st0 + 64] = va1.h.lo;
    *(short4v*)&v_t[st0 + 68] = va1.h.hi;
    va0.s = *(const short8*)(vgr + 128);             // tile 1 -> regs
    va1.s = *(const short8*)(vgr + 192);

    // PV read geometry: row c = (ch*32 + l31); b64 pair at (mb, mb+8) for ks0
    // and (mb+16, mb+24) for ks1, where mb = mh*32 + lh*4 (slot permutation).
    const int rA = l31 * 132;          // ch0 rows
    const int rB = (32 + l31) * 132;   // ch1 rows
    const int mb = (mh << 5) + (lh << 2);

    f32x16 z16, acc0, acc1;
#pragma unroll
    for (int r = 0; r < 16; ++r) { z16[r] = 0.f; acc0[r] = 0.f; acc1[r] = 0.f; }
    float ls = 0.f;

    barrier_lgkm();   // tile-0 staging visible; va/tile-1 loads stay in flight

#pragma unroll 2
    for (int it = 0; it < 32; ++it) {
        const int buf = (it & 1) * (CC * 132);
        const int nxt = ((it + 1) & 31) << 7;        // *128 (wrap: warm read)
        const int nx2 = ((it + 2) & 31) << 7;

        // top-of-iter global prefetches: consumed next iter -> full-iter
        // in-flight span, never drained by the lgkm-only barrier.
        vb0.s = *(const short8*)(vgr + nx2);
        vb1.s = *(const short8*)(vgr + nx2 + 64);
        if (lane < 32)
            kn = *(const short8*)(kws + (size_t)(bN + nxt + (mh << 5) + l31) * 8);

        // S^T tile: D[m][q], lane: q=l31, 16 m in regs
        f32x16 d = __builtin_amdgcn_mfma_f32_32x32x16_bf16(kf, qf, z16, 0, 0, 0);

        float p[16];
#pragma unroll
        for (int r = 0; r < 16; ++r) p[r] = __expf(d[r]);
        float s0 = 0.f, s1 = 0.f;
#pragma unroll
        for (int r = 0; r < 8; ++r) { s0 += p[2 * r]; s1 += p[2 * r + 1]; }
        ls += s0 + s1;

        // in-register D->A repack (slot order = native reg order per lane)
        SH8 A0, A1;
        A0.u.x = permpack(p[0],  p[1]);  A0.u.y = permpack(p[2],  p[3]);
        A0.u.z = permpack(p[4],  p[5]);  A0.u.w = permpack(p[6],  p[7]);
        A1.u.x = permpack(p[8],  p[9]);  A1.u.y = permpack(p[10], p[11]);
        A1.u.z = permpack(p[12], p[13]); A1.u.w = permpack(p[14], p[15]);

        // V B-frags with matching slot permutation (2x b64 each)
        SH8 B00, B01, B10, B11;
        B00.h.lo = *(const short4v*)&v_t[buf + rA + mb];
        B00.h.hi = *(const short4v*)&v_t[buf + rA + mb + 8];
        B01.h.lo = *(const short4v*)&v_t[buf + rB + mb];
        B01.h.hi = *(const short4v*)&v_t[buf + rB + mb + 8];
        B10.h.lo = *(const short4v*)&v_t[buf + rA + mb + 16];
        B10.h.hi = *(const short4v*)&v_t[buf + rA + mb + 24];
        B11.h.lo = *(const short4v*)&v_t[buf + rB + mb + 16];
        B11.h.hi = *(const short4v*)&v_t[buf + rB + mb + 24];

        acc0 = __builtin_amdgcn_mfma_f32_32x32x16_bf16(A0.s, B00.s, acc0, 0, 0, 0);
        acc1 = __builtin_amdgcn_mfma_f32_32x32x16_bf16(A0.s, B01.s, acc1, 0, 0, 0);
        acc0 = __builtin_amdgcn_mfma_f32_32x32x16_bf16(A1.s, B10.s, acc0, 0, 0, 0);
        acc1 = __builtin_amdgcn_mfma_f32_32x32x16_bf16(A1.s, B11.s, acc1, 0, 0, 0);

        // stage tile t+1 into the other buffer (all waves passed the previous
        // barrier, so nobody still reads it)
        const int ob = (CC * 132) - buf;             // the other buffer
        *(short4v*)&v_t[ob + st0]      = va0.h.lo;
        *(short4v*)&v_t[ob + st0 + 4]  = va0.h.hi;
        *(short4v*)&v_t[ob + st0 + 64] = va1.h.lo;
        *(short4v*)&v_t[ob + st0 + 68] = va1.h.hi;
        va0 = vb0; va1 = vb1;
        kf = kn;

        barrier_lgkm();   // LDS-only drain: prefetches stay in flight
    }

    // softmax denominators: lane pair (l, l+32) share q=l31, disjoint m
    float lt = ls + __shfl_xor(ls, 32, 64);
    if (lane < 32) l_part[(mh * 2 + qh) * 32 + l31] = lt;
    __syncthreads();       // also retires last v_t use before eb aliasing
    if (w < 2 && lane < 32) {
        float s = l_part[(0 * 2 + qh) * 32 + l31] + l_part[(1 * 2 + qh) * 32 + l31]
                + l_part[(2 * 2 + qh) * 32 + l31] + l_part[(3 * 2 + qh) * 32 + l31];
        l_inv[qh * 32 + l31] = gamma[0] / s;         // fold gamma into 1/l
    }

    // tree-reduce acc over the 4 m-chunks (blobs are opaque [lane][reg] dumps)
    if (mh >= 2) {
        float* e0 = &eb[(((mh - 2) << 2) + (qh << 1) + 0) * 1088 + lane * 17];
        float* e1 = &eb[(((mh - 2) << 2) + (qh << 1) + 1) * 1088 + lane * 17];
#pragma unroll
        for (int r = 0; r < 16; ++r) { e0[r] = acc0[r]; e1[r] = acc1[r]; }
    }
    __syncthreads();
    if (mh < 2) {
        const float* e0 = &eb[((mh << 2) + (qh << 1) + 0) * 1088 + lane * 17];
        const float* e1 = &eb[((mh << 2) + (qh << 1) + 1) * 1088 + lane * 17];
#pragma unroll
        for (int r = 0; r < 16; ++r) { acc0[r] += e0[r]; acc1[r] += e1[r]; }
    }
    __syncthreads();
    if (mh == 1) {
        float* e0 = &eb[((qh << 1) + 0) * 1088 + lane * 17];
        float* e1 = &eb[((qh << 1) + 1) * 1088 + lane * 17];
#pragma unroll
        for (int r = 0; r < 16; ++r) { e0[r] = acc0[r]; e1[r] = acc1[r]; }
    }
    __syncthreads();
    if (w < 2) {
        const float* e0 = &eb[((qh << 1) + 0) * 1088 + lane * 17];
        const float* e1 = &eb[((qh << 1) + 1) * 1088 + lane * 17];
#pragma unroll
        for (int r = 0; r < 16; ++r) { acc0[r] += e0[r]; acc1[r] += e1[r]; }
    }
    __syncthreads();       // blobs fully consumed before eb2 overwrite

    // scale & stage final [c][q] tile to LDS (stride 69: 5 mod 32 -> the
    // l31-indexed row writes and the (c,qo) reads are bank-conflict-free)
    if (w < 2) {
        // D rows: q = 8k + 4*lh + (r&3) for regs 4k..4k+3; col c = l31 (+32)
        f32x4 li[4];
#pragma unroll
        for (int k = 0; k < 4; ++k)
            li[k] = *(const f32x4*)&l_inv[qh * 32 + (k << 3) + (lh << 2)];
#pragma unroll
        for (int ch = 0; ch < 2; ++ch) {
            const int c = (ch << 5) + l31;
            const f32x16 a = ch ? acc1 : acc0;
            float* er = eb2 + c * 69 + (qh << 5) + (lh << 2);
#pragma unroll
            for (int k = 0; k < 4; ++k) {
#pragma unroll
                for (int r = 0; r < 4; ++r)
                    er[(k << 3) + r] = a[4 * k + r] * li[k][r];
            }
        }
    }
    __syncthreads();

    // all 512 threads: residual add + store, fully coalesced 32B/thread
    {
        const int c2 = tid >> 3;
        const int qo = (tid & 7) << 3;
        const float* er = eb2 + c2 * 69 + qo;
        const size_t rowb = (((size_t)((b << 6) + c2)) << 12) + qb + qo;
        const float4 x0 = *(const float4*)&x[rowb];
        const float4 x1 = *(const float4*)&x[rowb + 4];
        float4 o0, o1;
        o0.x = x0.x + er[0]; o0.y = x0.y + er[1];
        o0.z = x0.z + er[2]; o0.w = x0.w + er[3];
        o1.x = x1.x + er[4]; o1.y = x1.y + er[5];
        o1.z = x1.z + er[6]; o1.w = x1.w + er[7];
        *(float4*)&out[rowb]     = o0;
        *(float4*)&out[rowb + 4] = o1;
    }
}

// ---------------------------------------------------------------------------
extern "C" void kernel_launch(void* const* d_in, const int* in_sizes, int n_in,
                              void* d_out, int out_size, void* d_ws, size_t ws_size,
                              hipStream_t stream)
{
    const float* x     = (const float*)d_in[0];
    const float* wq    = (const float*)d_in[1];
    const float* bq    = (const float*)d_in[2];
    const float* wk    = (const float*)d_in[3];
    const float* bk    = (const float*)d_in[4];
    const float* wv    = (const float*)d_in[5];
    const float* bv    = (const float*)d_in[6];
    const float* gamma = (const float*)d_in[7];
    u16*   ws  = (u16*)d_ws;
    float* out = (float*)d_out;

    hipLaunchKernelGGL(proj_kernel, dim3(BB * NN / 512, 8), dim3(512), 0, stream,
                       x, wq, bq, wk, bk, wv, bv, ws);
    hipLaunchKernelGGL(attn_kernel, dim3(NN / 64, BB), dim3(512), 0, stream,
                       x, gamma, ws, out);
}

// Round 3
// 95.999 us; speedup vs baseline: 1.0853x; 1.0405x over previous
//
#include <hip/hip_runtime.h>

// (B,C,H,W) = (4,64,64,64) -> N=4096, Cr=8. Single-head attn, d_k=8, d_v=64.
#define BB 4
#define CC 64
#define NN 4096

typedef __attribute__((ext_vector_type(8)))  short short8;
typedef __attribute__((ext_vector_type(4)))  short short4v;
typedef __attribute__((ext_vector_type(2)))  float f32x2;
typedef __attribute__((ext_vector_type(4)))  float f32x4;
typedef __attribute__((ext_vector_type(16))) float f32x16;
typedef unsigned short u16;

// workspace (all bf16): qws [B*N][8] (PRE-SCALED by log2e in f32 before the
// bf16 round -> no extra rounding error vs unscaled), kws [B*N][8],
// vws [B*64][N] (V transposed)
#define QWS_ELEMS (BB * NN * 8)
#define LOG2E 1.4426950408889634f

// softmax exp: exp(d) = exp2(d*log2e) with the scale folded into Q at
// projection time -> ONE trans op, no v_mul. MUST go through the clang
// builtin (proper ISel -> TRANS-use hazard states inserted); a raw
// inline-asm v_exp_f32 produced NaN in an earlier round (hazard recognizer
// is keyed on producer opcode, which inline asm hides).
#if __has_builtin(__builtin_amdgcn_exp2f)
#define EXP2(x) __builtin_amdgcn_exp2f(x)
#else
#define EXP2(x) __expf((x) * 0.6931471805599453f)   // exp2 via exp fallback
#endif

__device__ inline u16 f2bf(float x) {
    unsigned u = __float_as_uint(x);
    u = (u + 0x7fffu + ((u >> 16) & 1u)) >> 16;   // RNE
    return (u16)u;
}
__device__ inline unsigned pack2rne(float a, float b) {
    return (unsigned)f2bf(a) | ((unsigned)f2bf(b) << 16);
}
// truncating bf16 pack of two floats in one v_perm_b32 (P only; 6x error headroom)
__device__ inline unsigned permpack(float lo, float hi) {
    return __builtin_amdgcn_perm(__float_as_uint(hi), __float_as_uint(lo), 0x07060302);
}

// Barrier with LDS-only drain: does NOT wait vmcnt, so global prefetches
// stay in flight across the barrier (correctness needs only ds ordering:
// staging ds_writes and fragment ds_reads both retire via lgkmcnt).
__device__ inline void barrier_lgkm() {
    asm volatile("s_waitcnt lgkmcnt(0)\n\ts_barrier" ::: "memory");
}

union SH8 {
    short8 s;
    struct Halves { short4v lo, hi; } h;
    uint4 u;
};

// ---------------------------------------------------------------------------
// Kernel 1: QKV projection. Grid (32, 8) x 512 thr = 256 blocks (1/CU),
// 1 pixel/thread. BALANCED slices: block y computes v[8y..8y+8) plus a
// 2-channel q-pair (y<4: q[2y,2y+1]) or k-pair (y>=4: k[2y-8,2y-7]) ->
// uniform 640 FMA/thread. Streaming form: one coalesced x load per channel
// feeding 10 FMAs. Q accumulators scaled by log2e (f32) before bf16 pack.
// ---------------------------------------------------------------------------
__global__ __launch_bounds__(512) void proj_kernel(
    const float* __restrict__ x,
    const float* __restrict__ wq, const float* __restrict__ bq,
    const float* __restrict__ wk, const float* __restrict__ bk,
    const float* __restrict__ wv, const float* __restrict__ bv,
    u16* __restrict__ ws_u)
{
    u16* qws = ws_u;
    u16* kws = ws_u + QWS_ELEMS;
    u16* vws = ws_u + 2 * QWS_ELEMS;

    const int y   = blockIdx.y;                    // 0..7, block-uniform
    const int pix = blockIdx.x * 512 + threadIdx.x;
    const int b   = pix >> 12;
    const int n   = pix & (NN - 1);
    const float* xb = x + ((size_t)b << 18) + n;

    const int v0  = y << 3;
    const int isq = (y < 4) ? 1 : 0;
    const int qc0 = (y & 3) << 1;                  // channel pair within q|k
    const float* wj = isq ? wq : wk;               // block-uniform -> SGPR
    const float* bj = isq ? bq : bk;

    float av[8];
    float a0 = bj[qc0], a1 = bj[qc0 + 1];
#pragma unroll
    for (int i = 0; i < 8; ++i) av[i] = bv[v0 + i];
#pragma unroll 8
    for (int c = 0; c < CC; ++c) {
        const float xv = xb[(size_t)c << 12];      // coalesced 256B/wave
#pragma unroll
        for (int i = 0; i < 8; ++i)
            av[i] += wv[(v0 + i) * CC + c] * xv;   // scalar (uniform) loads
        a0 += wj[qc0 * CC + c] * xv;
        a1 += wj[(qc0 + 1) * CC + c] * xv;
    }
#pragma unroll
    for (int i = 0; i < 8; ++i)
        vws[(((size_t)((b << 6) + v0 + i)) << 12) + n] = f2bf(av[i]);

    if (isq) { a0 *= LOG2E; a1 *= LOG2E; }         // fold exp->exp2 scale into Q
    u16* dst = (isq ? qws : kws) + (size_t)pix * 8 + qc0;
    *(unsigned*)dst = pack2rne(a0, a1);            // 4B store (even u16 offset)
}

// ---------------------------------------------------------------------------
// Kernel 2: fused 32x32x16-MFMA flash attention. Block 512 thr (8 waves =
// 4 m-chunks x 2 q-halves), 64 q/block, 16 iters x 256 keys (two 128-key
// sub-tiles per barrier; 4 LDS V-buffers in 2 pairs), ONE lgkm-only barrier
// per iter (global prefetches never drained). S^T = K*Q^T per wave; exp2'd
// S D-frag (Q pre-scaled by log2e) repacked IN-REGISTER to the PV A-frag
// via a permuted k-slot order; V B-frags gathered from LDS with the SAME
// permutation (2x ds_read_b64 each). P never touches LDS. V staged
// global->LDS pair-double-buffered (132-u16 padded rows). Prefetches issued
// at top-of-iter for max in-flight span. Per-wave PV partials tree-reduced;
// epilogue stages scaled result to LDS so ALL 512 threads do the residual
// add with coalesced 32B x/out accesses.
// ---------------------------------------------------------------------------
#define CC132 (CC * 132)               // u16 elems per 128-key V buffer

__global__ __launch_bounds__(512) void attn_kernel(
    const float* __restrict__ x, const float* __restrict__ gamma,
    const u16* __restrict__ ws_u, float* __restrict__ out)
{
    const u16* qws = ws_u;
    const u16* kws = ws_u + QWS_ELEMS;
    const u16* vws = ws_u + 2 * QWS_ELEMS;

    // smem: v_t [4][CC132] u16 (67584 B) ALIASED with eb [8][64*17] f32
    // (34816 B, reduce blobs) ALIASED with eb2 [64][69] f32 (17664 B, final
    // staging), then l_part, l_inv.
    __shared__ __align__(16) char smem[67584 + 1024 + 256];
    u16*   v_t    = (u16*)smem;                    // [4][CC132]
    float* eb     = (float*)smem;                  // [8][64*17]
    float* eb2    = (float*)smem;                  // [64][69]
    float* l_part = (float*)(smem + 67584);        // [8][32]
    float* l_inv  = (float*)(smem + 67584 + 1024); // [2][32], holds gamma/l

    const int tid  = threadIdx.x;
    const int w    = tid >> 6;
    const int lane = tid & 63;
    const int l31  = lane & 31;
    const int lh   = lane >> 5;
    const int mh   = w >> 1;       // 0..3 m-chunk
    const int qh   = w & 1;        // 0..1 q-half

    const int b  = blockIdx.y;
    const int qb = blockIdx.x << 6;   // 64 queries/block
    const int bN = b << 12;

    // S fragments (lanes>=32 supply k-slots 8..15 = zero; only 8 real ch)
    short8 qf  = {0,0,0,0,0,0,0,0};
    short8 kf0 = {0,0,0,0,0,0,0,0};
    short8 kf1 = {0,0,0,0,0,0,0,0};
    if (lane < 32) {
        qf  = *(const short8*)(qws + (size_t)(bN + qb + (qh << 5) + l31) * 8);
        kf0 = *(const short8*)(kws + (size_t)(bN + (mh << 5) + l31) * 8);        // tile 0
        kf1 = *(const short8*)(kws + (size_t)(bN + 128 + (mh << 5) + l31) * 8);  // tile 1
    }
    short8 kn0 = kf0, kn1 = kf1;

    // V staging: thread -> (row c_st, octets o_st, o_st+64) of a 128-m tile
    const int c_st = tid >> 3;
    const int o_st = (tid & 7) << 3;                 // u16 offset of octet
    const u16* vgr = vws + (((size_t)((b << 6) + c_st)) << 12) + o_st;
    const int st0  = c_st * 132 + o_st;              // 132-u16 padded rows

    SH8 va0, va1, va2, va3, vb0, vb1, vb2, vb3;
    va0.s = *(const short8*)(vgr);                   // tile 0
    va1.s = *(const short8*)(vgr + 64);
    va2.s = *(const short8*)(vgr + 128);             // tile 1
    va3.s = *(const short8*)(vgr + 192);
    // stage tiles 0,1 -> pair 0 (bufs 0,1)
    *(short4v*)&v_t[st0]              = va0.h.lo;    // b64 writes (8B-aligned)
    *(short4v*)&v_t[st0 + 4]          = va0.h.hi;
    *(short4v*)&v_t[st0 + 64]         = va1.h.lo;
    *(short4v*)&v_t[st0 + 68]         = va1.h.hi;
    *(short4v*)&v_t[CC132 + st0]      = va2.h.lo;
    *(short4v*)&v_t[CC132 + st0 + 4]  = va2.h.hi;
    *(short4v*)&v_t[CC132 + st0 + 64] = va3.h.lo;
    *(short4v*)&v_t[CC132 + st0 + 68] = va3.h.hi;
    va0.s = *(const short8*)(vgr + 256);             // tiles 2,3 -> regs
    va1.s = *(const short8*)(vgr + 320);
    va2.s = *(const short8*)(vgr + 384);
    va3.s = *(const short8*)(vgr + 448);

    // PV read geometry: row c = (ch*32 + l31); b64 pair at (mb, mb+8) for ks0
    // and (mb+16, mb+24) for ks1, where mb = mh*32 + lh*4 (slot permutation).
    const int rA = l31 * 132;          // ch0 rows
    const int rB = (32 + l31) * 132;   // ch1 rows
    const int mb = (mh << 5) + (lh << 2);

    f32x16 z16, acc0, acc1;
#pragma unroll
    for (int r = 0; r < 16; ++r) { z16[r] = 0.f; acc0[r] = 0.f; acc1[r] = 0.f; }
    f32x2 ls2 = {0.f, 0.f};

    barrier_lgkm();   // pair-0 staging visible; tile-2/3 loads stay in flight

    // one 128-key sub-tile: S^T mfma -> exp2 -> pk-sum -> in-reg repack ->
    // V B-frags from LDS buffer at BUFOFF -> 4 PV mfma into acc0/acc1
#define SUBTILE(KF, BUFOFF)                                                    \
    {                                                                          \
        f32x16 d = __builtin_amdgcn_mfma_f32_32x32x16_bf16(KF, qf, z16, 0, 0, 0); \
        float p[16];                                                           \
        _Pragma("unroll")                                                      \
        for (int r = 0; r < 16; ++r) p[r] = EXP2(d[r]);                        \
        f32x2 s2 = {0.f, 0.f};                                                 \
        _Pragma("unroll")                                                      \
        for (int r = 0; r < 8; ++r) {                                          \
            f32x2 t = {p[2 * r], p[2 * r + 1]};                                \
            s2 += t;                                                           \
        }                                                                      \
        ls2 += s2;                                                             \
        SH8 A0, A1;                                                            \
        A0.u.x = permpack(p[0],  p[1]);  A0.u.y = permpack(p[2],  p[3]);       \
        A0.u.z = permpack(p[4],  p[5]);  A0.u.w = permpack(p[6],  p[7]);       \
        A1.u.x = permpack(p[8],  p[9]);  A1.u.y = permpack(p[10], p[11]);      \
        A1.u.z = permpack(p[12], p[13]); A1.u.w = permpack(p[14], p[15]);      \
        SH8 B00, B01, B10, B11;                                                \
        B00.h.lo = *(const short4v*)&v_t[(BUFOFF) + rA + mb];                  \
        B00.h.hi = *(const short4v*)&v_t[(BUFOFF) + rA + mb + 8];              \
        B01.h.lo = *(const short4v*)&v_t[(BUFOFF) + rB + mb];                  \
        B01.h.hi = *(const short4v*)&v_t[(BUFOFF) + rB + mb + 8];              \
        B10.h.lo = *(const short4v*)&v_t[(BUFOFF) + rA + mb + 16];             \
        B10.h.hi = *(const short4v*)&v_t[(BUFOFF) + rA + mb + 24];             \
        B11.h.lo = *(const short4v*)&v_t[(BUFOFF) + rB + mb + 16];             \
        B11.h.hi = *(const short4v*)&v_t[(BUFOFF) + rB + mb + 24];             \
        acc0 = __builtin_amdgcn_mfma_f32_32x32x16_bf16(A0.s, B00.s, acc0, 0, 0, 0); \
        acc1 = __builtin_amdgcn_mfma_f32_32x32x16_bf16(A0.s, B01.s, acc1, 0, 0, 0); \
        acc0 = __builtin_amdgcn_mfma_f32_32x32x16_bf16(A1.s, B10.s, acc0, 0, 0, 0); \
        acc1 = __builtin_amdgcn_mfma_f32_32x32x16_bf16(A1.s, B11.s, acc1, 0, 0, 0); \
    }

#pragma unroll 2
    for (int i = 0; i < 16; ++i) {
        const int pb = (i & 1) * (2 * CC132);        // pair read this iter
        const int ob = (2 * CC132) - pb;             // pair staged this iter
        const int nk = ((2 * i + 2) & 31) << 7;      // K keys for tiles 2i+2,2i+3
        const int nv = ((2 * i + 4) & 31) << 7;      // V keys for tiles 2i+4,2i+5

        // top-of-iter global prefetches: consumed next iter -> full-iter
        // in-flight span, never drained by the lgkm-only barrier.
        vb0.s = *(const short8*)(vgr + nv);
        vb1.s = *(const short8*)(vgr + nv + 64);
        vb2.s = *(const short8*)(vgr + nv + 128);
        vb3.s = *(const short8*)(vgr + nv + 192);
        if (lane < 32) {
            kn0 = *(const short8*)(kws + (size_t)(bN + nk + (mh << 5) + l31) * 8);
            kn1 = *(const short8*)(kws + (size_t)(bN + nk + 128 + (mh << 5) + l31) * 8);
        }

        SUBTILE(kf0, pb)                             // keys [256i, 256i+128)
        SUBTILE(kf1, pb + CC132)                     // keys [256i+128, 256i+256)

        // stage tiles 2i+2,2i+3 into the other pair (all waves passed the
        // previous barrier, so nobody still reads it)
        *(short4v*)&v_t[ob + st0]              = va0.h.lo;
        *(short4v*)&v_t[ob + st0 + 4]          = va0.h.hi;
        *(short4v*)&v_t[ob + st0 + 64]         = va1.h.lo;
        *(short4v*)&v_t[ob + st0 + 68]         = va1.h.hi;
        *(short4v*)&v_t[ob + CC132 + st0]      = va2.h.lo;
        *(short4v*)&v_t[ob + CC132 + st0 + 4]  = va2.h.hi;
        *(short4v*)&v_t[ob + CC132 + st0 + 64] = va3.h.lo;
        *(short4v*)&v_t[ob + CC132 + st0 + 68] = va3.h.hi;
        va0 = vb0; va1 = vb1; va2 = vb2; va3 = vb3;
        kf0 = kn0; kf1 = kn1;

        barrier_lgkm();   // LDS-only drain: prefetches stay in flight
    }
#undef SUBTILE

    float ls = ls2.x + ls2.y;

    // softmax denominators: lane pair (l, l+32) share q=l31, disjoint m
    float lt = ls + __shfl_xor(ls, 32, 64);
    if (lane < 32) l_part[(mh * 2 + qh) * 32 + l31] = lt;
    __syncthreads();       // also retires last v_t use before eb aliasing
    if (w < 2 && lane < 32) {
        float s = l_part[(0 * 2 + qh) * 32 + l31] + l_part[(1 * 2 + qh) * 32 + l31]
                + l_part[(2 * 2 + qh) * 32 + l31] + l_part[(3 * 2 + qh) * 32 + l31];
        l_inv[qh * 32 + l31] = gamma[0] / s;         // fold gamma into 1/l
    }

    // tree-reduce acc over the 4 m-chunks (blobs are opaque [lane][reg] dumps)
    if (mh >= 2) {
        float* e0 = &eb[(((mh - 2) << 2) + (qh << 1) + 0) * 1088 + lane * 17];
        float* e1 = &eb[(((mh - 2) << 2) + (qh << 1) + 1) * 1088 + lane * 17];
#pragma unroll
        for (int r = 0; r < 16; ++r) { e0[r] = acc0[r]; e1[r] = acc1[r]; }
    }
    __syncthreads();
    if (mh < 2) {
        const float* e0 = &eb[((mh << 2) + (qh << 1) + 0) * 1088 + lane * 17];
        const float* e1 = &eb[((mh << 2) + (qh << 1) + 1) * 1088 + lane * 17];
#pragma unroll
        for (int r = 0; r < 16; ++r) { acc0[r] += e0[r]; acc1[r] += e1[r]; }
    }
    __syncthreads();
    if (mh == 1) {
        float* e0 = &eb[((qh << 1) + 0) * 1088 + lane * 17];
        float* e1 = &eb[((qh << 1) + 1) * 1088 + lane * 17];
#pragma unroll
        for (int r = 0; r < 16; ++r) { e0[r] = acc0[r]; e1[r] = acc1[r]; }
    }
    __syncthreads();
    if (w < 2) {
        const float* e0 = &eb[((qh << 1) + 0) * 1088 + lane * 17];
        const float* e1 = &eb[((qh << 1) + 1) * 1088 + lane * 17];
#pragma unroll
        for (int r = 0; r < 16; ++r) { acc0[r] += e0[r]; acc1[r] += e1[r]; }
    }
    __syncthreads();       // blobs fully consumed before eb2 overwrite

    // scale & stage final [c][q] tile to LDS (stride 69: 5 mod 32 -> the
    // l31-indexed row writes and the (c,qo) reads are bank-conflict-free)
    if (w < 2) {
        // D rows: q = 8k + 4*lh + (r&3) for regs 4k..4k+3; col c = l31 (+32)
        f32x4 li[4];
#pragma unroll
        for (int k = 0; k < 4; ++k)
            li[k] = *(const f32x4*)&l_inv[qh * 32 + (k << 3) + (lh << 2)];
#pragma unroll
        for (int ch = 0; ch < 2; ++ch) {
            const int c = (ch << 5) + l31;
            const f32x16 a = ch ? acc1 : acc0;
            float* er = eb2 + c * 69 + (qh << 5) + (lh << 2);
#pragma unroll
            for (int k = 0; k < 4; ++k) {
#pragma unroll
                for (int r = 0; r < 4; ++r)
                    er[(k << 3) + r] = a[4 * k + r] * li[k][r];
            }
        }
    }
    __syncthreads();

    // all 512 threads: residual add + store, fully coalesced 32B/thread
    {
        const int c2 = tid >> 3;
        const int qo = (tid & 7) << 3;
        const float* er = eb2 + c2 * 69 + qo;
        const size_t rowb = (((size_t)((b << 6) + c2)) << 12) + qb + qo;
        const float4 x0 = *(const float4*)&x[rowb];
        const float4 x1 = *(const float4*)&x[rowb + 4];
        float4 o0, o1;
        o0.x = x0.x + er[0]; o0.y = x0.y + er[1];
        o0.z = x0.z + er[2]; o0.w = x0.w + er[3];
        o1.x = x1.x + er[4]; o1.y = x1.y + er[5];
        o1.z = x1.z + er[6]; o1.w = x1.w + er[7];
        *(float4*)&out[rowb]     = o0;
        *(float4*)&out[rowb + 4] = o1;
    }
}

// ---------------------------------------------------------------------------
extern "C" void kernel_launch(void* const* d_in, const int* in_sizes, int n_in,
                              void* d_out, int out_size, void* d_ws, size_t ws_size,
                              hipStream_t stream)
{
    const float* x     = (const float*)d_in[0];
    const float* wq    = (const float*)d_in[1];
    const float* bq    = (const float*)d_in[2];
    const float* wk    = (const float*)d_in[3];
    const float* bk    = (const float*)d_in[4];
    const float* wv    = (const float*)d_in[5];
    const float* bv    = (const float*)d_in[6];
    const float* gamma = (const float*)d_in[7];
    u16*   ws  = (u16*)d_ws;
    float* out = (float*)d_out;

    hipLaunchKernelGGL(proj_kernel, dim3(BB * NN / 512, 8), dim3(512), 0, stream,
                       x, wq, bq, wk, bk, wv, bv, ws);
    hipLaunchKernelGGL(attn_kernel, dim3(NN / 64, BB), dim3(512), 0, stream,
                       x, gamma, ws, out);
}